// Round 6
// baseline (1348.530 us; speedup 1.0000x reference)
//
#include <hip/hip_runtime.h>

// ---------------------------------------------------------------------------
// OT_Attn: unbalanced Sinkhorn on MI355X.
// R6: per-thread dataflow pull. R5's exchange had 5 serialized fabric hops
// (drain -> blkflag -> aggregator -> root -> tid0 detect -> global burst).
// Now: producer drains + stores blkflag[bid]; consumer THREAD t spins on
// blkflag[t] alone (64B-padded line, == compare: poison-safe, monotonic-safe
// by the structural argument: producer can't publish iter k+1 before every
// block consumed iter k), then immediately pulls chunk t (contiguous 128B/64B)
// and scatters to LDS. Tail chunk dominates; earlier chunks overlap.
// Transport = only the R3/R5-validated relaxed AGENT __hip_atomic ops.
// LDS scatter is ~32-way bank-aliased (64B lane stride) -- ~0.2us, accepted.
// ---------------------------------------------------------------------------

#define NROWS 4096
#define MCOLS 2048
#define NITER 100
#define NBLK  256   // 1 block/CU (LDS-bound), grid == CU count -> co-resident

using short8  = __attribute__((ext_vector_type(8))) short;
using floatx4 = __attribute__((ext_vector_type(4))) float;

__device__ __forceinline__ float bf2f(unsigned short u) {
  return __uint_as_float(((unsigned)u) << 16);
}
__device__ __forceinline__ unsigned short f2bf(float f) {  // RNE
  unsigned u = __float_as_uint(f);
  u += 0x7fffu + ((u >> 16) & 1u);
  return (unsigned short)(u >> 16);
}
__device__ __forceinline__ float powfi(float x, float fi) {
  return __expf(fi * __logf(x));
}
__device__ __forceinline__ unsigned long long packvt(float v, unsigned tag) {
  return ((unsigned long long)tag << 32) | (unsigned long long)__float_as_uint(v);
}
__device__ __forceinline__ unsigned aload(const unsigned* p) {
  return __hip_atomic_load(p, __ATOMIC_RELAXED, __HIP_MEMORY_SCOPE_AGENT);
}
__device__ __forceinline__ void astore(unsigned* p, unsigned v) {
  __hip_atomic_store(p, v, __ATOMIC_RELAXED, __HIP_MEMORY_SCOPE_AGENT);
}
__device__ __forceinline__ unsigned long long aload64(const unsigned long long* p) {
  return __hip_atomic_load(p, __ATOMIC_RELAXED, __HIP_MEMORY_SCOPE_AGENT);
}

// ---------------------------------------------------------------------------
__global__ void zero_kernel(unsigned* maxCbits, float* out) {
  if (threadIdx.x == 0) { *maxCbits = 0u; out[8388608] = 0.0f; }
}

// ---------------------------------------------------------------------------
// One block per row (4096 x-rows then 2048 y-rows): min-shift, bf16 round,
// squared norm OF THE ROUNDED VALUES (consistent with the bf16 GEMM).
__global__ __launch_bounds__(256) void prep_kernel(
    const float* __restrict__ x, const float* __restrict__ y,
    unsigned short* __restrict__ xb, unsigned short* __restrict__ yb,
    float* __restrict__ nx, float* __restrict__ ny) {
  const int row = blockIdx.x;
  const int tid = threadIdx.x;
  const float* src; unsigned short* dst; float* nd;
  if (row < NROWS) { src = x + (size_t)row * 1024; dst = xb + (size_t)row * 1024; nd = nx + row; }
  else { const int r = row - NROWS; src = y + (size_t)r * 1024; dst = yb + (size_t)r * 1024; nd = ny + r; }

  float4 v = ((const float4*)src)[tid];
  float mn = fminf(fminf(v.x, v.y), fminf(v.z, v.w));
  #pragma unroll
  for (int m = 1; m < 64; m <<= 1) mn = fminf(mn, __shfl_xor(mn, m));
  __shared__ float wred[4];
  const int w = tid >> 6, l = tid & 63;
  if (l == 0) wred[w] = mn;
  __syncthreads();
  mn = fminf(fminf(wred[0], wred[1]), fminf(wred[2], wred[3]));
  __syncthreads();   // wred reused below

  const unsigned short b0 = f2bf(v.x - mn), b1 = f2bf(v.y - mn);
  const unsigned short b2 = f2bf(v.z - mn), b3 = f2bf(v.w - mn);
  ushort4 ub; ub.x = b0; ub.y = b1; ub.z = b2; ub.w = b3;
  ((ushort4*)dst)[tid] = ub;
  const float f0 = bf2f(b0), f1 = bf2f(b1), f2 = bf2f(b2), f3 = bf2f(b3);
  float acc = f0 * f0 + f1 * f1 + f2 * f2 + f3 * f3;
  #pragma unroll
  for (int m = 1; m < 64; m <<= 1) acc += __shfl_xor(acc, m);
  if (l == 0) wred[w] = acc;
  __syncthreads();
  if (tid == 0) *nd = wred[0] + wred[1] + wred[2] + wred[3];
}

// ---------------------------------------------------------------------------
// C[i][j] = max(nx_i + ny_j - 2*dot(xb_i, yb_j), 0).  128x128 block tile,
// 4 waves as 2x2, each wave 64x64 = 4x4 MFMA 16x16x32 tiles.
__global__ __launch_bounds__(256) void cost_gemm_kernel(
    const unsigned short* __restrict__ xb, const unsigned short* __restrict__ yb,
    const float* __restrict__ nx, const float* __restrict__ ny,
    float* __restrict__ C, unsigned* __restrict__ maxCbits) {
  const int tid = threadIdx.x;
  const int w = tid >> 6, l = tid & 63;
  const int wr = w >> 1, wc = w & 1;
  const int i0 = blockIdx.y * 128 + wr * 64;
  const int j0 = blockIdx.x * 128 + wc * 64;
  const int m16 = l & 15, q = l >> 4;

  const unsigned short* ap = xb + (size_t)(i0 + m16) * 1024 + q * 8;
  const unsigned short* bp = yb + (size_t)(j0 + m16) * 1024 + q * 8;

  floatx4 acc[4][4];
  #pragma unroll
  for (int a = 0; a < 4; ++a)
    #pragma unroll
    for (int b = 0; b < 4; ++b) acc[a][b] = (floatx4){0.f, 0.f, 0.f, 0.f};

  for (int k0 = 0; k0 < 1024; k0 += 32) {
    short8 av[4], bv[4];
    #pragma unroll
    for (int t = 0; t < 4; ++t) av[t] = *(const short8*)(ap + (size_t)t * 16 * 1024 + k0);
    #pragma unroll
    for (int t = 0; t < 4; ++t) bv[t] = *(const short8*)(bp + (size_t)t * 16 * 1024 + k0);
    #pragma unroll
    for (int ti = 0; ti < 4; ++ti)
      #pragma unroll
      for (int tj = 0; tj < 4; ++tj)
        acc[ti][tj] = __builtin_amdgcn_mfma_f32_16x16x32_bf16(av[ti], bv[tj], acc[ti][tj], 0, 0, 0);
  }

  float mx = 0.f;
  #pragma unroll
  for (int ti = 0; ti < 4; ++ti) {
    #pragma unroll
    for (int tj = 0; tj < 4; ++tj) {
      const int i = i0 + ti * 16 + q * 4;       // C/D: row = quad*4+reg
      const int j = j0 + tj * 16 + m16;         //       col = lane&15
      const float nyj = ny[j];
      #pragma unroll
      for (int r = 0; r < 4; ++r) {
        float c = nx[i + r] + nyj - 2.0f * acc[ti][tj][r];
        c = fmaxf(c, 0.0f);
        C[(size_t)(i + r) * 2048 + j] = c;
        mx = fmaxf(mx, c);
      }
    }
  }
  __shared__ float mred[4];
  #pragma unroll
  for (int m = 1; m < 64; m <<= 1) mx = fmaxf(mx, __shfl_xor(mx, m));
  if (l == 0) mred[w] = mx;
  __syncthreads();
  if (tid == 0) {
    const float bm = fmaxf(fmaxf(mred[0], mred[1]), fmaxf(mred[2], mred[3]));
    atomicMax(maxCbits, __float_as_uint(bm));
  }
}

// ---------------------------------------------------------------------------
// Persistent dataflow Sinkhorn. Block b: rows [16b,16b+16) via Ks, columns
// [8b,8b+8) via KsT. Per iteration it (tag = it):
//   pass1 -> publish 16 tagged u's -> drain -> blkflag[bid]
//     thread t: spin blkflag[t]==it -> pull uglob[16t..16t+16) -> us LDS
//   pass2 -> publish 8 tagged v's -> drain -> blkflag[bid]
//     thread t: spin vblkflag[t]==it -> pull vglob[8t..8t+8) -> vs LDS
__global__ __launch_bounds__(256) void sinkhorn_kernel(
    const float* __restrict__ C, const unsigned* __restrict__ maxCbits,
    unsigned long long* __restrict__ uglob, unsigned long long* __restrict__ vglob,
    unsigned* __restrict__ ublkflag, unsigned* __restrict__ vblkflag,
    float* __restrict__ out) {
  __shared__ __align__(16) unsigned short Ks[16 * 2048];   // 64 KB rows
  __shared__ __align__(16) unsigned short KsT[8 * 4096];   // 64 KB cols
  __shared__ __align__(16) float us[4096];                 // 16 KB
  __shared__ __align__(16) float vs[2048];                 // 8 KB
  __shared__ __align__(16) float uloc[16];
  __shared__ float dred[4];

  const int tid = threadIdx.x;
  const int bid = blockIdx.x;
  const int w = tid >> 6, l = tid & 63;
  const int i0 = bid * 16;
  const int jb = bid * 8;

  const float fi = 0.8333333333333334f;   // 0.5/(0.5+0.1)
  const float av = 1.0f / 4096.0f;
  const float bv = 1.0f / 2048.0f;

  // ---- prologue: Ks rows + KsT cols from C (identical exp/round both sides),
  //      v = 1/m
  {
    const float sc = -1.0f / (0.1f * __uint_as_float(*maxCbits));
    for (int il = 0; il < 16; ++il) {
      const float* cp = C + (size_t)(i0 + il) * 2048 + tid * 8;
      const float4 c0 = *(const float4*)cp;
      const float4 c1 = *(const float4*)(cp + 4);
      uint4 pk;
      pk.x = (unsigned)f2bf(__expf(c0.x * sc)) | ((unsigned)f2bf(__expf(c0.y * sc)) << 16);
      pk.y = (unsigned)f2bf(__expf(c0.z * sc)) | ((unsigned)f2bf(__expf(c0.w * sc)) << 16);
      pk.z = (unsigned)f2bf(__expf(c1.x * sc)) | ((unsigned)f2bf(__expf(c1.y * sc)) << 16);
      pk.w = (unsigned)f2bf(__expf(c1.z * sc)) | ((unsigned)f2bf(__expf(c1.w * sc)) << 16);
      *(uint4*)&Ks[il * 2048 + tid * 8] = pk;
    }
    // KsT: column slice C[:, jb..jb+8), strided gather (one-time cost)
    #pragma unroll
    for (int k = 0; k < 16; ++k) {
      const int i = tid + (k << 8);
      const float* cp = C + (size_t)i * 2048 + jb;
      const float4 c0 = *(const float4*)cp;
      const float4 c1 = *(const float4*)(cp + 4);
      KsT[0 * 4096 + i] = f2bf(__expf(c0.x * sc));
      KsT[1 * 4096 + i] = f2bf(__expf(c0.y * sc));
      KsT[2 * 4096 + i] = f2bf(__expf(c0.z * sc));
      KsT[3 * 4096 + i] = f2bf(__expf(c0.w * sc));
      KsT[4 * 4096 + i] = f2bf(__expf(c1.x * sc));
      KsT[5 * 4096 + i] = f2bf(__expf(c1.y * sc));
      KsT[6 * 4096 + i] = f2bf(__expf(c1.z * sc));
      KsT[7 * 4096 + i] = f2bf(__expf(c1.w * sc));
    }
    const float4 vinit = make_float4(bv, bv, bv, bv);
    *(float4*)&vs[tid * 8] = vinit;
    *(float4*)&vs[tid * 8 + 4] = vinit;
  }
  __syncthreads();

  for (int it = 1; it <= NITER; ++it) {
    const unsigned tagit = (unsigned)it;

    // ---- pass 1: wave w rows w*4..w*4+3; u = (a/(K v))^fi; publish tagged
    float part[4] = {0.f, 0.f, 0.f, 0.f};
    const int r0 = w * 4;
    #pragma unroll
    for (int c = 0; c < 4; ++c) {
      const int j0 = c * 512 + l * 8;
      const float4 va = *(const float4*)&vs[j0];
      const float4 vb = *(const float4*)&vs[j0 + 4];
      #pragma unroll
      for (int rr = 0; rr < 4; ++rr) {
        const uint4 kb = *(const uint4*)&Ks[(r0 + rr) * 2048 + j0];
        part[rr] += bf2f((unsigned short)kb.x) * va.x + bf2f((unsigned short)(kb.x >> 16)) * va.y
                 +  bf2f((unsigned short)kb.y) * va.z + bf2f((unsigned short)(kb.y >> 16)) * va.w
                 +  bf2f((unsigned short)kb.z) * vb.x + bf2f((unsigned short)(kb.z >> 16)) * vb.y
                 +  bf2f((unsigned short)kb.w) * vb.z + bf2f((unsigned short)(kb.w >> 16)) * vb.w;
      }
    }
    #pragma unroll
    for (int m = 1; m < 64; m <<= 1) {
      part[0] += __shfl_xor(part[0], m);
      part[1] += __shfl_xor(part[1], m);
      part[2] += __shfl_xor(part[2], m);
      part[3] += __shfl_xor(part[3], m);
    }
    if (l == 0) {
      #pragma unroll
      for (int r = 0; r < 4; ++r) {
        const float uv = powfi(av / part[r], fi);
        uloc[r0 + r] = uv;
        __hip_atomic_store(&uglob[i0 + r0 + r], packvt(uv, tagit),
                           __ATOMIC_RELAXED, __HIP_MEMORY_SCOPE_AGENT);
      }
    }
    __syncthreads();   // drains all waves' stores (vmcnt 0) before flagging
    if (tid == 0) astore(&ublkflag[bid * 16], tagit);

    // ---- u exchange: thread t spins on blkflag[t], pulls chunk t -> LDS
    {
      while (aload(&ublkflag[tid * 16]) != tagit) __builtin_amdgcn_s_sleep(1);
      unsigned long long g[16];
      unsigned pend = 0xFFFFu;
      do {
        #pragma unroll
        for (int k = 0; k < 16; ++k)
          if (pend & (1u << k))
            g[k] = aload64(&uglob[tid * 16 + k]);
        #pragma unroll
        for (int k = 0; k < 16; ++k)
          if ((pend & (1u << k)) && (unsigned)(g[k] >> 32) == tagit)
            pend &= ~(1u << k);
      } while (pend);   // backstop; expected 1 round (flag => data ordering)
      float* ud = &us[tid * 16];
      #pragma unroll
      for (int k = 0; k < 4; ++k)
        *(float4*)(ud + 4 * k) = make_float4(
            __uint_as_float((unsigned)g[4 * k + 0]),
            __uint_as_float((unsigned)g[4 * k + 1]),
            __uint_as_float((unsigned)g[4 * k + 2]),
            __uint_as_float((unsigned)g[4 * k + 3]));
    }
    __syncthreads();

    // ---- pass 2: wave w owns cols jb+2w, jb+2w+1; t_j local via KsT
    {
      float t0 = 0.f, t1 = 0.f;
      const int ca = (2 * w) * 4096;
      const int cb = (2 * w + 1) * 4096;
      #pragma unroll
      for (int c = 0; c < 8; ++c) {
        const int ic = c * 512 + l * 8;
        const float4 ua = *(const float4*)&us[ic];
        const float4 ub = *(const float4*)&us[ic + 4];
        const uint4 ka = *(const uint4*)&KsT[ca + ic];
        const uint4 kb = *(const uint4*)&KsT[cb + ic];
        t0 += bf2f((unsigned short)ka.x) * ua.x + bf2f((unsigned short)(ka.x >> 16)) * ua.y
           +  bf2f((unsigned short)ka.y) * ua.z + bf2f((unsigned short)(ka.y >> 16)) * ua.w
           +  bf2f((unsigned short)ka.z) * ub.x + bf2f((unsigned short)(ka.z >> 16)) * ub.y
           +  bf2f((unsigned short)ka.w) * ub.z + bf2f((unsigned short)(ka.w >> 16)) * ub.w;
        t1 += bf2f((unsigned short)kb.x) * ua.x + bf2f((unsigned short)(kb.x >> 16)) * ua.y
           +  bf2f((unsigned short)kb.y) * ua.z + bf2f((unsigned short)(kb.y >> 16)) * ua.w
           +  bf2f((unsigned short)kb.z) * ub.x + bf2f((unsigned short)(kb.z >> 16)) * ub.y
           +  bf2f((unsigned short)kb.w) * ub.z + bf2f((unsigned short)(kb.w >> 16)) * ub.w;
      }
      #pragma unroll
      for (int m = 1; m < 64; m <<= 1) {
        t0 += __shfl_xor(t0, m);
        t1 += __shfl_xor(t1, m);
      }
      if (l == 0) {
        __hip_atomic_store(&vglob[jb + 2 * w], packvt(powfi(bv / t0, fi), tagit),
                           __ATOMIC_RELAXED, __HIP_MEMORY_SCOPE_AGENT);
        __hip_atomic_store(&vglob[jb + 2 * w + 1], packvt(powfi(bv / t1, fi), tagit),
                           __ATOMIC_RELAXED, __HIP_MEMORY_SCOPE_AGENT);
      }
    }
    __syncthreads();   // drains stores
    if (tid == 0) astore(&vblkflag[bid * 16], tagit);

    // ---- v exchange: thread t spins on vblkflag[t], pulls chunk t -> LDS
    {
      while (aload(&vblkflag[tid * 16]) != tagit) __builtin_amdgcn_s_sleep(1);
      unsigned long long g[8];
      unsigned pend = 0xFFu;
      do {
        #pragma unroll
        for (int k = 0; k < 8; ++k)
          if (pend & (1u << k))
            g[k] = aload64(&vglob[tid * 8 + k]);
        #pragma unroll
        for (int k = 0; k < 8; ++k)
          if ((pend & (1u << k)) && (unsigned)(g[k] >> 32) == tagit)
            pend &= ~(1u << k);
      } while (pend);
      float* vd = &vs[tid * 8];
      #pragma unroll
      for (int k = 0; k < 2; ++k)
        *(float4*)(vd + 4 * k) = make_float4(
            __uint_as_float((unsigned)g[4 * k + 0]),
            __uint_as_float((unsigned)g[4 * k + 1]),
            __uint_as_float((unsigned)g[4 * k + 2]),
            __uint_as_float((unsigned)g[4 * k + 3]));
    }
    __syncthreads();
  }

  // ---- epilogue: flow.T[j][i0..i0+15] (64B contiguous stores) + dist
  float ur[16];
  *(float4*)&ur[0]  = *(const float4*)&uloc[0];
  *(float4*)&ur[4]  = *(const float4*)&uloc[4];
  *(float4*)&ur[8]  = *(const float4*)&uloc[8];
  *(float4*)&ur[12] = *(const float4*)&uloc[12];
  float distp = 0.f;
  for (int sub = 0; sub < 8; ++sub) {
    const int j = w * 512 + sub * 64 + l;
    const float vj = vs[j];
    float o[16];
    #pragma unroll
    for (int il = 0; il < 16; ++il) {
      const float kf = bf2f(Ks[il * 2048 + j]);
      const float fl = ur[il] * kf * vj;
      o[il] = fl;
      distp += C[(size_t)(i0 + il) * 2048 + j] * fl;
    }
    float* op = out + (size_t)j * 4096 + i0;
    *(float4*)(op)      = make_float4(o[0],  o[1],  o[2],  o[3]);
    *(float4*)(op + 4)  = make_float4(o[4],  o[5],  o[6],  o[7]);
    *(float4*)(op + 8)  = make_float4(o[8],  o[9],  o[10], o[11]);
    *(float4*)(op + 12) = make_float4(o[12], o[13], o[14], o[15]);
  }
  #pragma unroll
  for (int m = 1; m < 64; m <<= 1) distp += __shfl_xor(distp, m);
  if (l == 0) dred[w] = distp;
  __syncthreads();
  if (tid == 0) unsafeAtomicAdd(out + (size_t)8388608, dred[0] + dred[1] + dred[2] + dred[3]);
}

// ---------------------------------------------------------------------------
extern "C" void kernel_launch(void* const* d_in, const int* in_sizes, int n_in,
                              void* d_out, int out_size, void* d_ws, size_t ws_size,
                              hipStream_t stream) {
  (void)in_sizes; (void)n_in; (void)out_size; (void)ws_size;
  const float* x = (const float*)d_in[0];
  const float* y = (const float*)d_in[1];
  float* out = (float*)d_out;
  char* ws = (char*)d_ws;

  // workspace layout (bytes)
  float*              Cmat     = (float*)(ws + 0);                 // 32 MB
  unsigned short*     xb       = (unsigned short*)(ws + 33554432); // 8 MB
  unsigned short*     yb       = (unsigned short*)(ws + 41943040); // 4 MB
  float*              nx       = (float*)(ws + 46137344);          // 16 KB
  float*              ny       = (float*)(ws + 46153728);          // 8 KB
  unsigned*           maxC     = (unsigned*)(ws + 46161920);
  unsigned long long* uglob    = (unsigned long long*)(ws + 46162432); // 32 KB
  unsigned long long* vglob    = (unsigned long long*)(ws + 46195200); // 16 KB
  unsigned*           ublkflag = (unsigned*)(ws + 46211584);       // 256x64B
  unsigned*           vblkflag = (unsigned*)(ws + 46227968);       // 256x64B

  hipLaunchKernelGGL(zero_kernel, dim3(1), dim3(64), 0, stream, maxC, out);
  hipLaunchKernelGGL(prep_kernel, dim3(6144), dim3(256), 0, stream, x, y, xb, yb, nx, ny);
  hipLaunchKernelGGL(cost_gemm_kernel, dim3(16, 32), dim3(256), 0, stream, xb, yb, nx, ny, Cmat, maxC);
  hipLaunchKernelGGL(sinkhorn_kernel, dim3(NBLK), dim3(256), 0, stream,
                     Cmat, maxC, uglob, vglob, ublkflag, vblkflag, out);
}